// Round 3
// baseline (521.389 us; speedup 1.0000x reference)
//
#include <hip/hip_runtime.h>
#include <hip/hip_bf16.h>

#define BATCH 4096
#define NB    64
#define DM    256
#define KSW   8      // k-steps of W (256/32)
#define KST   10     // total k-steps incl. 2 bias-identity steps (K=320)
#define NBPB  8      // batches per persistent block
#define GRID  (BATCH / NBPB)   // 512 blocks -> 2 per CU (LDS-limited at 64 KB)

typedef __bf16 bf16x8 __attribute__((ext_vector_type(8)));
typedef float  f32x4  __attribute__((ext_vector_type(4)));

union Frag16 { uint4 u; bf16x8 b; ushort s[8]; };
union Pk2    { __hip_bfloat162 v; unsigned u; };

__device__ __forceinline__ ushort f2bf(float x) {
    unsigned u = __float_as_uint(x);
    return (ushort)((u + 0x7FFFu + ((u >> 16) & 1u)) >> 16);   // RNE, finite inputs
}
__device__ __forceinline__ unsigned pk2(float a, float b) {
    Pk2 p; p.v = __float22bfloat162_rn(make_float2(a, b));     // v_cvt_pk_bf16_f32
    return p.u;
}
__device__ __forceinline__ float bf2f(ushort u) {
    return __uint_as_float(((unsigned)u) << 16);
}

// ---- pre-pass: swizzle [W ; ba] (K=320) into bf16 B-fragment order ----
__global__ void swizzle_WB(const float* __restrict__ W, const float* __restrict__ ba,
                           ushort* __restrict__ Wf) {
    int idx  = blockIdx.x * 256 + threadIdx.x;   // 0..10239
    int lane = idx & 63;
    int g    = idx >> 6;                         // 0..159
    int et   = g / KST;
    int ks   = g % KST;
    int e    = et * 16 + (lane & 15);
    int r0   = (ks < KSW) ? ks * 32 : (ks - KSW) * 32;
    r0 += ((lane >> 4) << 3);
    const float* src = (ks < KSW) ? W : ba;
    Frag16 f;
#pragma unroll
    for (int j = 0; j < 8; ++j)
        f.s[j] = f2bf(src[(r0 + j) * DM + e]);
    reinterpret_cast<uint4*>(Wf)[idx] = f.u;
}

// ---- fused, persistent, double-buffered across batches ----
__global__ __launch_bounds__(256, 2) void aspect_attn(
    const float*  __restrict__ h,
    const ushort* __restrict__ Wf,
    float*        __restrict__ out)
{
    __shared__ __align__(16) ushort Hs[2 * 16384];   // 2 x 32 KB frag-order H buffers

    const int tid  = threadIdx.x;
    const int wave = tid >> 6;
    const int lane = tid & 63;
    const int quad = lane >> 4;
    const int l15  = lane & 15;
    const int b0   = blockIdx.x * NBPB;

    const uint4* WfB = reinterpret_cast<const uint4*>(Wf);

    // per-thread staging geometry: slot = it*256 + tid; frag f = it*4 + wave
    // row = ((f>>3)<<4)|l15 ; k0 = ((f&7)<<5)|(quad<<3) ; global float offset = row*DM + k0
    int goff[8];
#pragma unroll
    for (int it = 0; it < 8; ++it) {
        int f = it * 4 + wave;
        int row = ((f >> 3) << 4) | l15;
        int k0  = ((f & 7) << 5) | (quad << 3);
        goff[it] = row * DM + k0;
    }

    // ---- prologue: stage batch b0 into buffer 0 ----
    {
        const float* hb = h + (size_t)b0 * (NB * DM);
#pragma unroll
        for (int it = 0; it < 8; ++it) {
            const f32x4* p = reinterpret_cast<const f32x4*>(hb + goff[it]);
            f32x4 a = p[0], c = p[1];
            uint4 o;
            o.x = pk2(a.x, a.y); o.y = pk2(a.z, a.w);
            o.z = pk2(c.x, c.y); o.w = pk2(c.z, c.w);
            reinterpret_cast<uint4*>(Hs)[it * 256 + tid] = o;
        }
    }
    __syncthreads();

    int cur = 0;
    for (int i = 0; i < NBPB; ++i) {
        const int b = b0 + i;

        // 1. issue prefetch loads for batch i+1 (in flight across GEMM+epilogue)
        f32x4 ld[16];
        const bool havenext = (i + 1 < NBPB);
        if (havenext) {
            const float* hn = h + (size_t)(b + 1) * (NB * DM);
#pragma unroll
            for (int it = 0; it < 8; ++it) {
                const f32x4* p = reinterpret_cast<const f32x4*>(hn + goff[it]);
                ld[2 * it]     = p[0];
                ld[2 * it + 1] = p[1];
            }
        }

        // 2. GEMM: wave w computes S[0:64][64w:64w+64], K=320 (bias folded)
        f32x4 acc[4][4];
#pragma unroll
        for (int mt = 0; mt < 4; ++mt)
#pragma unroll
            for (int nt = 0; nt < 4; ++nt) {
                f32x4 z = {0.f, 0.f, 0.f, 0.f};
                acc[mt][nt] = z;
            }

        const uint4* HsB = reinterpret_cast<const uint4*>(Hs) + cur * 2048;
#pragma unroll
        for (int ks = 0; ks < KSW; ++ks) {
            Frag16 af[4], bfr[4];
#pragma unroll
            for (int mt = 0; mt < 4; ++mt)
                af[mt].u = HsB[(mt * 8 + ks) * 64 + lane];
#pragma unroll
            for (int nt = 0; nt < 4; ++nt)
                bfr[nt].u = WfB[((wave * 4 + nt) * KST + ks) * 64 + lane];
#pragma unroll
            for (int mt = 0; mt < 4; ++mt)
#pragma unroll
                for (int nt = 0; nt < 4; ++nt)
                    acc[mt][nt] = __builtin_amdgcn_mfma_f32_16x16x32_bf16(
                        af[mt].b, bfr[nt].b, acc[mt][nt], 0, 0, 0);
        }
        // bias fold: 2 k-steps with identity A-fragments (register-generated)
#pragma unroll
        for (int kx = 0; kx < 2; ++kx) {
            Frag16 af[4], bfr[4];
#pragma unroll
            for (int nt = 0; nt < 4; ++nt)
                bfr[nt].u = WfB[((wave * 4 + nt) * KST + KSW + kx) * 64 + lane];
            const int kb = kx * 32 + quad * 8;
#pragma unroll
            for (int mt = 0; mt < 4; ++mt) {
                int d = (mt * 16 + l15) - kb;
#pragma unroll
                for (int j = 0; j < 8; ++j)
                    af[mt].s[j] = (d == j) ? (ushort)0x3F80 : (ushort)0;
            }
#pragma unroll
            for (int mt = 0; mt < 4; ++mt)
#pragma unroll
                for (int nt = 0; nt < 4; ++nt)
                    acc[mt][nt] = __builtin_amdgcn_mfma_f32_16x16x32_bf16(
                        af[mt].b, bfr[nt].b, acc[mt][nt], 0, 0, 0);
        }

        // 3a. tanh (bounded => no softmax max-shift)
#pragma unroll
        for (int mt = 0; mt < 4; ++mt)
#pragma unroll
            for (int nt = 0; nt < 4; ++nt)
#pragma unroll
                for (int r = 0; r < 4; ++r) {
                    float x = acc[mt][nt][r];
                    float e = __expf(-2.f * fabsf(x));
                    float t = (1.f - e) * __builtin_amdgcn_rcpf(1.f + e);
                    acc[mt][nt][r] = copysignf(t, x);
                }

        // 3b. softmax over n (column's 64 rows live across the 4 quads)
#pragma unroll
        for (int nt = 0; nt < 4; ++nt) {
            float ls = 0.f;
#pragma unroll
            for (int mt = 0; mt < 4; ++mt)
#pragma unroll
                for (int r = 0; r < 4; ++r) {
                    float p = __expf(acc[mt][nt][r]);   // s in (-1,1): safe
                    acc[mt][nt][r] = p;
                    ls += p;
                }
            ls += __shfl_xor(ls, 16, 64);
            ls += __shfl_xor(ls, 32, 64);
            float inv = __builtin_amdgcn_rcpf(ls);
#pragma unroll
            for (int mt = 0; mt < 4; ++mt)
#pragma unroll
                for (int r = 0; r < 4; ++r)
                    acc[mt][nt][r] *= inv;
        }

        // 3c. out[n] = sum_e a[n,e]*h[n,e]; wave-partial then 4-lane atomicAdd
        const int colb = wave * 64;
        const ushort* Hcur = Hs + cur * 16384;
#pragma unroll
        for (int mt = 0; mt < 4; ++mt)
#pragma unroll
            for (int r = 0; r < 4; ++r) {
                const int row  = mt * 16 + quad * 4 + r;
                const int ridx = mt * 4096 + (quad * 4 + r) * 8;
                float s = 0.f;
#pragma unroll
                for (int nt = 0; nt < 4; ++nt) {
                    int col  = colb + nt * 16 + l15;
                    int coff = (col >> 5) * 512 + ((col >> 3) & 3) * 128 + (col & 7);
                    s += acc[mt][nt][r] * bf2f(Hcur[ridx + coff]);
                }
#pragma unroll
                for (int m = 1; m < 16; m <<= 1)
                    s += __shfl_xor(s, m, 64);
                if (l15 == 0)
                    atomicAdd(out + (size_t)b * NB + row, s);
            }

        // 4. convert prefetched regs -> other buffer (the only vmcnt wait)
        if (havenext) {
            uint4* dst = reinterpret_cast<uint4*>(Hs) + (cur ^ 1) * 2048;
#pragma unroll
            for (int it = 0; it < 8; ++it) {
                f32x4 a = ld[2 * it], c = ld[2 * it + 1];
                uint4 o;
                o.x = pk2(a.x, a.y); o.y = pk2(a.z, a.w);
                o.z = pk2(c.x, c.y); o.w = pk2(c.z, c.w);
                dst[it * 256 + tid] = o;
            }
        }
        __syncthreads();   // clean drain: no outstanding staging loads here
        cur ^= 1;
    }
}

extern "C" void kernel_launch(void* const* d_in, const int* in_sizes, int n_in,
                              void* d_out, int out_size, void* d_ws, size_t ws_size,
                              hipStream_t stream) {
    const float* h  = (const float*)d_in[0];   // [4096, 64, 256] fp32
    const float* W  = (const float*)d_in[1];   // [256, 256] fp32
    const float* ba = (const float*)d_in[2];   // [64, 256] fp32
    float* out = (float*)d_out;                // [4096, 64] fp32
    ushort* Wf = (ushort*)d_ws;                // 160 KB swizzled bf16 [W ; ba]

    hipMemsetAsync(out, 0, (size_t)out_size * sizeof(float), stream);
    swizzle_WB<<<40, 256, 0, stream>>>(W, ba, Wf);
    aspect_attn<<<GRID, 256, 0, stream>>>(h, Wf, out);
}